// Round 2
// baseline (364.019 us; speedup 1.0000x reference)
//
#include <hip/hip_runtime.h>

// Problem constants
constexpr int kH  = 8;     // heads
constexpr int kD  = 16;    // dim per head
constexpr int kHD = 128;   // H*D
constexpr int kN  = 32;    // neighbors
constexpr int kE  = 32;    // edge feature dim
constexpr int kD0 = 128;   // feats0 channels
constexpr int kD1 = 64;    // feats1 channels
constexpr int kP  = 4;     // positions per block (k1)
constexpr int kP3 = 2;     // positions per block (k3)
constexpr int kPP = 8;     // positions per block (k4)

constexpr float SCALE0   = 0.25f;                 // 1/sqrt(16)
constexpr float SCALE1   = 0.14433756729740643f;  // 1/sqrt(48)
constexpr float SHARED_S = 0.70710678118654752f;  // sqrt(0.5)
constexpr float NEGV     = -1e9f;

// ws layout (floats): sc[n][272] | sv0[n][128] | sv1[n][384]
// After k3_accum, sv0/sv1 are reused in-place as o0/o1 (attn-weighted V sums).

// ---------------------------------------------------------------------------
// K1: self key/value rows + null/self similarity score slots. P positions/block.
// ---------------------------------------------------------------------------
__global__ __launch_bounds__(256) void k1_selfkv(
    const float* __restrict__ q0, const float* __restrict__ q1,
    const float* __restrict__ feats0, const float* __restrict__ feats1,
    const float* __restrict__ Wskv0, const float* __restrict__ Wskv1,
    const float* __restrict__ self_bias, const float* __restrict__ null_bias,
    const float* __restrict__ nk0, const float* __restrict__ nk1,
    const float* __restrict__ hw1,
    float* __restrict__ ws_sc, float* __restrict__ ws_sv0, float* __restrict__ ws_sv1)
{
  const int i0 = blockIdx.x * kP;
  const int t  = threadIdx.x;
  __shared__ __align__(16) float f0s[kP][kD0];
  __shared__ __align__(16) float f1s[kP][kD1 * 3];
  __shared__ __align__(16) float q0s[kP][kHD];
  __shared__ __align__(16) float q1s[kP][kHD * 3];
  __shared__ float sk0L[kP][kHD];
  __shared__ float sk1L[kP][kHD * 3];
  __shared__ float w1s[kH];

  for (int u = t; u < kP * 32; u += 256) { int p = u >> 5, r = u & 31;
    ((float4*)f0s[p])[r] = ((const float4*)(feats0 + (size_t)(i0 + p) * kD0))[r]; }
  for (int u = t; u < kP * 48; u += 256) { int p = u / 48, r = u % 48;
    ((float4*)f1s[p])[r] = ((const float4*)(feats1 + (size_t)(i0 + p) * kD1 * 3))[r]; }
  for (int u = t; u < kP * 32; u += 256) { int p = u >> 5, r = u & 31;
    ((float4*)q0s[p])[r] = ((const float4*)(q0 + (size_t)(i0 + p) * kHD))[r]; }
  for (int u = t; u < kP * 96; u += 256) { int p = u / 96, r = u % 96;
    ((float4*)q1s[p])[r] = ((const float4*)(q1 + (size_t)(i0 + p) * kHD * 3))[r]; }
  if (t < kH) w1s[t] = log1pf(expf(hw1[t]));
  __syncthreads();

  float acc0[kP] = {};
  {
    const float4* wr = (const float4*)(Wskv0 + t * kD0);
    #pragma unroll
    for (int g = 0; g < 32; ++g) {
      float4 w = wr[g]; int c = g * 4;
      #pragma unroll
      for (int p = 0; p < kP; ++p)
        acc0[p] += w.x * f0s[p][c] + w.y * f0s[p][c + 1]
                 + w.z * f0s[p][c + 2] + w.w * f0s[p][c + 3];
    }
  }
  float acc1[kP][3] = {};
  {
    const float4* wr = (const float4*)(Wskv1 + t * kD1);
    #pragma unroll
    for (int g = 0; g < 16; ++g) {
      float4 w = wr[g]; int c = g * 4;
      float wv[4] = {w.x, w.y, w.z, w.w};
      #pragma unroll
      for (int q = 0; q < 4; ++q) {
        #pragma unroll
        for (int p = 0; p < kP; ++p) {
          const float* fp = &f1s[p][(c + q) * 3];
          acc1[p][0] += wv[q] * fp[0];
          acc1[p][1] += wv[q] * fp[1];
          acc1[p][2] += wv[q] * fp[2];
        }
      }
    }
  }
  if (t < kHD) {
    #pragma unroll
    for (int p = 0; p < kP; ++p) {
      sk0L[p][t] = acc0[p];
      sk1L[p][t * 3 + 0] = acc1[p][0];
      sk1L[p][t * 3 + 1] = acc1[p][1];
      sk1L[p][t * 3 + 2] = acc1[p][2];
    }
  } else {
    const int o = t - kHD;
    #pragma unroll
    for (int p = 0; p < kP; ++p) {
      ws_sv0[(size_t)(i0 + p) * kHD + o] = acc0[p];
      float* sp = ws_sv1 + (size_t)(i0 + p) * kHD * 3 + o * 3;
      sp[0] = acc1[p][0]; sp[1] = acc1[p][1]; sp[2] = acc1[p][2];
    }
  }
  __syncthreads();

  if (t < kP * 16) {
    const int p = t >> 4, idx = t & 15;
    const int h = idx & 7;
    const bool is_self = idx >= 8;
    float s0 = 0.f, s1 = 0.f, bias;
    if (is_self) {
      #pragma unroll
      for (int d = 0; d < kD; ++d) s0 += q0s[p][h * kD + d] * sk0L[p][h * kD + d];
      #pragma unroll
      for (int x = 0; x < 48; ++x) s1 += q1s[p][h * 48 + x] * sk1L[p][h * 48 + x];
      bias = self_bias[h];
    } else {
      #pragma unroll
      for (int d = 0; d < kD; ++d) s0 += q0s[p][h * kD + d] * nk0[h * kD + d];
      #pragma unroll
      for (int x = 0; x < 48; ++x) s1 += q1s[p][h * 48 + x] * nk1[h * 48 + x];
      bias = null_bias[h];
    }
    float total = (s0 * SCALE0 + bias + s1 * SCALE1 * w1s[h]) * SHARED_S;
    ws_sc[(size_t)(i0 + p) * 272 + h * 34 + (is_self ? 1 : 0)] = total;
  }
}

// ---------------------------------------------------------------------------
// K2: neighbor similarities + fused softmax. ONE position per block (2048
// blocks -> 8 blocks/CU; was 512 blocks = 2/CU = the occupancy limiter).
// Thread layout t = h*32 + j: each head's 32 neighbor scores sit in 32
// contiguous lanes -> softmax fully via __shfl_xor (masks 16..1 stay inside
// the 32-lane group). No score LDS buffer, one barrier total, LDS ~7 KB.
// ---------------------------------------------------------------------------
__global__ __launch_bounds__(256) void k2_sims(
    const float* __restrict__ q0, const float* __restrict__ q1,
    const float* __restrict__ k0, const float* __restrict__ k1,
    const float* __restrict__ edges, const float* __restrict__ Wbias,
    const float* __restrict__ hw1, const int* __restrict__ nmask,
    float* __restrict__ ws_sc)
{
  const int i = blockIdx.x;
  const int t = threadIdx.x;
  __shared__ __align__(16) float q0s[kHD];          // 128
  __shared__ __align__(16) float q1s[kHD * 3];      // 384
  __shared__ __align__(16) float edg[kN][kE + 1];   // 32 x 33 (pad: conflict-free)
  __shared__ float wbs[kH * kE];                    // [h][e]
  __shared__ float w1s[kH];

  // stage q, edges, Wbias
  if (t < 32) {
    ((float4*)q0s)[t] = ((const float4*)(q0 + (size_t)i * kHD))[t];
  } else if (t < 128) {
    int r = t - 32;
    ((float4*)q1s)[r] = ((const float4*)(q1 + (size_t)i * kHD * 3))[r];
  }
  {
    float4 v = ((const float4*)(edges + (size_t)i * kN * kE))[t];
    int j = t >> 3, e4 = (t & 7) * 4;
    float* dst = &edg[j][e4];
    dst[0] = v.x; dst[1] = v.y; dst[2] = v.z; dst[3] = v.w;
  }
  if (t < kH * kE) wbs[t] = Wbias[t];               // already [h][e] row-major
  if (t < kH) w1s[t] = log1pf(expf(hw1[t]));
  __syncthreads();

  const int h = t >> 5, j = t & 31;

  // pair bias: edg[j][:] . Wbias[h][:]  (edg pad-33 -> conflict-free; wbs
  // broadcast within each 32-lane head group)
  float bias = 0.f;
  #pragma unroll
  for (int e = 0; e < kE; ++e) bias += edg[j][e] * wbs[h * kE + e];

  // degree-0 similarity
  float s0 = 0.f;
  const float4* kr0 = (const float4*)(k0 + ((size_t)i * kN + j) * kHD + h * kD);
  #pragma unroll
  for (int g = 0; g < 4; ++g) {
    float4 w = kr0[g]; int x = h * kD + g * 4;
    s0 += w.x * q0s[x] + w.y * q0s[x + 1] + w.z * q0s[x + 2] + w.w * q0s[x + 3];
  }
  // degree-1 similarity
  float s1 = 0.f;
  const float4* kr1 = (const float4*)(k1 + ((size_t)i * kN + j) * kHD * 3 + h * 48);
  #pragma unroll
  for (int g = 0; g < 12; ++g) {
    float4 w = kr1[g]; int x = h * 48 + g * 4;
    s1 += w.x * q1s[x] + w.y * q1s[x + 1] + w.z * q1s[x + 2] + w.w * q1s[x + 3];
  }

  float total = (s0 * SCALE0 + bias + s1 * SCALE1 * w1s[h]) * SHARED_S;
  bool valid = nmask[(size_t)i * kN + j] != 0;
  float sc = valid ? total : NEGV;

  // null/self slots (written by k1) — same 2 addresses for the 32-lane group
  float* row = ws_sc + (size_t)i * 272 + h * 34;
  float e0v = row[0], e1v = row[1];

  // softmax over 34 = {null, self, 32 neighbors}; shuffle-reduce the 32 lanes
  float mx = sc;
  #pragma unroll
  for (int off = 16; off > 0; off >>= 1) mx = fmaxf(mx, __shfl_xor(mx, off));
  mx = fmaxf(mx, fmaxf(e0v, e1v));
  float ex = __expf(sc - mx);
  float sum = ex;
  #pragma unroll
  for (int off = 16; off > 0; off >>= 1) sum += __shfl_xor(sum, off);
  float ee0 = __expf(e0v - mx), ee1 = __expf(e1v - mx);
  float inv = 1.f / (sum + ee0 + ee1);

  row[2 + j] = ex * inv;
  if (j == 0) row[0] = ee0 * inv;
  if (j == 1) row[1] = ee1 * inv;
}

// ---------------------------------------------------------------------------
// K3: attn-weighted V accumulation ONLY (projection split into k4_proj).
// One (position, float4-chunk) per thread; batched loads (8 in flight).
// Writes o0/o1 IN PLACE over ws_sv0/ws_sv1: each thread reads its sv chunk
// before writing its o chunk at the same address (same thread, race-free).
// __launch_bounds__(256,4): cap VGPR<=128 -> 16 waves/CU.
// ---------------------------------------------------------------------------
__global__ __launch_bounds__(256, 4) void k3_accum(
    const float* __restrict__ v0, const float* __restrict__ v1,
    const float* __restrict__ nv0, const float* __restrict__ nv1,
    const float* __restrict__ ws_sc,
    float* __restrict__ ws_sv0, float* __restrict__ ws_sv1)
{
  const int i0 = blockIdx.x * kP3;
  const int t  = threadIdx.x;
  __shared__ __align__(16) float attnL[kP3][272];

  if (t < kP3 * 68) {
    int p = t / 68, r = t % 68;
    ((float4*)attnL[p])[r] = ((const float4*)(ws_sc + (size_t)(i0 + p) * 272))[r];
  }
  __syncthreads();

  // thread -> (p, s): p = t>>7, s = t&127. s<32: deg0 chunk s; else deg1 chunk s-32.
  const int p = t >> 7, i = i0 + p;
  const int s = t & 127;
  float4 acc;
  if (s < 32) {
    const int h = s >> 2;
    const float* at = attnL[p] + h * 34;
    float4 nv = ((const float4*)nv0)[s];
    float4 sv = ((const float4*)(ws_sv0 + (size_t)i * kHD))[s];
    acc.x = at[0] * nv.x + at[1] * sv.x;
    acc.y = at[0] * nv.y + at[1] * sv.y;
    acc.z = at[0] * nv.z + at[1] * sv.z;
    acc.w = at[0] * nv.w + at[1] * sv.w;
    const float4* vp = (const float4*)(v0 + (size_t)i * kN * kHD) + s;
    float4 vbuf[8];
    #pragma unroll
    for (int g = 0; g < 4; ++g) {
      #pragma unroll
      for (int r = 0; r < 8; ++r) vbuf[r] = vp[(g * 8 + r) * 32];
      #pragma unroll
      for (int r = 0; r < 8; ++r) {
        float a = at[2 + g * 8 + r];
        acc.x += a * vbuf[r].x; acc.y += a * vbuf[r].y;
        acc.z += a * vbuf[r].z; acc.w += a * vbuf[r].w;
      }
    }
    ((float4*)(ws_sv0 + (size_t)i * kHD))[s] = acc;   // o0 overlays sv0
  } else {
    const int s1 = s - 32;            // 0..95, never straddles a head (48%4==0)
    const int h = s1 / 12;
    const float* at = attnL[p] + h * 34;
    float4 nv = ((const float4*)nv1)[s1];
    float4 sv = ((const float4*)(ws_sv1 + (size_t)i * kHD * 3))[s1];
    acc.x = at[0] * nv.x + at[1] * sv.x;
    acc.y = at[0] * nv.y + at[1] * sv.y;
    acc.z = at[0] * nv.z + at[1] * sv.z;
    acc.w = at[0] * nv.w + at[1] * sv.w;
    const float4* vp = (const float4*)(v1 + (size_t)i * kN * kHD * 3) + s1;
    float4 vbuf[8];
    #pragma unroll
    for (int g = 0; g < 4; ++g) {
      #pragma unroll
      for (int r = 0; r < 8; ++r) vbuf[r] = vp[(g * 8 + r) * 96];
      #pragma unroll
      for (int r = 0; r < 8; ++r) {
        float a = at[2 + g * 8 + r];
        acc.x += a * vbuf[r].x; acc.y += a * vbuf[r].y;
        acc.z += a * vbuf[r].z; acc.w += a * vbuf[r].w;
      }
    }
    ((float4*)(ws_sv1 + (size_t)i * kHD * 3))[s1] = acc;  // o1 overlays sv1
  }
}

// ---------------------------------------------------------------------------
// K4: output projections. kPP=8 positions/block, 320 threads (one per output
// column: 128 deg0 + 192 deg1). W rows amortized over 8 positions. o0/o1
// staged in LDS (16.5 KB).
// ---------------------------------------------------------------------------
__global__ __launch_bounds__(320) void k4_proj(
    const float* __restrict__ ws_o0, const float* __restrict__ ws_o1,
    const float* __restrict__ Wout0, const float* __restrict__ Wout1,
    float* __restrict__ out, int n_total)
{
  const int i0 = blockIdx.x * kPP;
  const int t  = threadIdx.x;
  __shared__ __align__(16) float o0L[kPP][kHD];
  __shared__ __align__(16) float o1L[kPP][kHD * 3];

  for (int u = t; u < kPP * 32; u += 320) { int p = u >> 5, r = u & 31;
    ((float4*)o0L[p])[r] = ((const float4*)(ws_o0 + (size_t)(i0 + p) * kHD))[r]; }
  for (int u = t; u < kPP * 96; u += 320) { int p = u / 96, r = u % 96;
    ((float4*)o1L[p])[r] = ((const float4*)(ws_o1 + (size_t)(i0 + p) * kHD * 3))[r]; }
  __syncthreads();

  if (t < 128) {
    float acc[kPP] = {};
    const float4* wr = (const float4*)(Wout0 + t * kHD);
    #pragma unroll
    for (int g = 0; g < 32; ++g) {
      float4 w = wr[g]; int c = g * 4;
      #pragma unroll
      for (int p = 0; p < kPP; ++p)
        acc[p] += w.x * o0L[p][c] + w.y * o0L[p][c + 1]
                + w.z * o0L[p][c + 2] + w.w * o0L[p][c + 3];
    }
    #pragma unroll
    for (int p = 0; p < kPP; ++p) out[(size_t)(i0 + p) * kHD + t] = acc[p];
  } else {
    const int v2 = t - 128, o = v2 / 3, m = v2 - o * 3;
    float acc[kPP] = {};
    const float4* wr = (const float4*)(Wout1 + o * kHD);
    #pragma unroll
    for (int g = 0; g < 32; ++g) {
      float4 w = wr[g]; int c = g * 4;
      #pragma unroll
      for (int p = 0; p < kPP; ++p)
        acc[p] += w.x * o1L[p][(c + 0) * 3 + m] + w.y * o1L[p][(c + 1) * 3 + m]
                + w.z * o1L[p][(c + 2) * 3 + m] + w.w * o1L[p][(c + 3) * 3 + m];
    }
    #pragma unroll
    for (int p = 0; p < kPP; ++p)
      out[(size_t)n_total * kHD + (size_t)(i0 + p) * 192 + v2] = acc[p];
  }
}

extern "C" void kernel_launch(void* const* d_in, const int* in_sizes, int n_in,
                              void* d_out, int out_size, void* d_ws, size_t ws_size,
                              hipStream_t stream) {
  const int n = in_sizes[0] / kHD;  // 2048
  const float* q0     = (const float*)d_in[0];
  const float* k0     = (const float*)d_in[1];
  const float* v0     = (const float*)d_in[2];
  const float* q1     = (const float*)d_in[3];
  const float* k1     = (const float*)d_in[4];
  const float* v1     = (const float*)d_in[5];
  const float* feats0 = (const float*)d_in[6];
  const float* feats1 = (const float*)d_in[7];
  const float* edges  = (const float*)d_in[8];
  const float* Wskv0  = (const float*)d_in[9];
  const float* Wskv1  = (const float*)d_in[10];
  const float* Wbias  = (const float*)d_in[11];
  const float* sbias  = (const float*)d_in[12];
  const float* nbias  = (const float*)d_in[13];
  const float* nk0    = (const float*)d_in[14];
  const float* nv0    = (const float*)d_in[15];
  const float* nk1    = (const float*)d_in[16];
  const float* nv1    = (const float*)d_in[17];
  const float* hw1    = (const float*)d_in[18];
  const float* Wout0  = (const float*)d_in[19];
  const float* Wout1  = (const float*)d_in[20];
  const int*   nmask  = (const int*)d_in[21];

  float* ws     = (float*)d_ws;
  float* ws_sc  = ws;                                      // n*272
  float* ws_sv0 = ws + (size_t)n * 272;                    // n*128 (then o0)
  float* ws_sv1 = ws + (size_t)n * 272 + (size_t)n * 128;  // n*384 (then o1)

  k1_selfkv<<<n / kP, 256, 0, stream>>>(q0, q1, feats0, feats1, Wskv0, Wskv1,
                                        sbias, nbias, nk0, nk1, hw1,
                                        ws_sc, ws_sv0, ws_sv1);
  k2_sims<<<n, 256, 0, stream>>>(q0, q1, k0, k1, edges, Wbias, hw1, nmask, ws_sc);
  k3_accum<<<n / kP3, 256, 0, stream>>>(v0, v1, nv0, nv1, ws_sc, ws_sv0, ws_sv1);
  k4_proj<<<n / kPP, 320, 0, stream>>>(ws_sv0, ws_sv1, Wout0, Wout1, (float*)d_out, n);
}

// Round 3
// 349.854 us; speedup vs baseline: 1.0405x; 1.0405x over previous
//
#include <hip/hip_runtime.h>

// Problem constants
constexpr int kH  = 8;     // heads
constexpr int kD  = 16;    // dim per head
constexpr int kHD = 128;   // H*D
constexpr int kN  = 32;    // neighbors
constexpr int kE  = 32;    // edge feature dim
constexpr int kD0 = 128;   // feats0 channels
constexpr int kD1 = 64;    // feats1 channels
constexpr int kP  = 4;     // positions per block (k1)
constexpr int kP3 = 2;     // positions per block (k3)
constexpr int kPP = 8;     // positions per block (k4)

constexpr float SCALE0   = 0.25f;                 // 1/sqrt(16)
constexpr float SCALE1   = 0.14433756729740643f;  // 1/sqrt(48)
constexpr float SHARED_S = 0.70710678118654752f;  // sqrt(0.5)
constexpr float NEGV     = -1e9f;

// ws layout (floats): sc[n][272] | sv0[n][128] | sv1[n][384]
// After k3_accum, sv0/sv1 are reused in-place as o0/o1 (attn-weighted V sums).

// ---------------------------------------------------------------------------
// K1: self key/value rows + null/self similarity score slots. P positions/block.
// ---------------------------------------------------------------------------
__global__ __launch_bounds__(256) void k1_selfkv(
    const float* __restrict__ q0, const float* __restrict__ q1,
    const float* __restrict__ feats0, const float* __restrict__ feats1,
    const float* __restrict__ Wskv0, const float* __restrict__ Wskv1,
    const float* __restrict__ self_bias, const float* __restrict__ null_bias,
    const float* __restrict__ nk0, const float* __restrict__ nk1,
    const float* __restrict__ hw1,
    float* __restrict__ ws_sc, float* __restrict__ ws_sv0, float* __restrict__ ws_sv1)
{
  const int i0 = blockIdx.x * kP;
  const int t  = threadIdx.x;
  __shared__ __align__(16) float f0s[kP][kD0];
  __shared__ __align__(16) float f1s[kP][kD1 * 3];
  __shared__ __align__(16) float q0s[kP][kHD];
  __shared__ __align__(16) float q1s[kP][kHD * 3];
  __shared__ float sk0L[kP][kHD];
  __shared__ float sk1L[kP][kHD * 3];
  __shared__ float w1s[kH];

  for (int u = t; u < kP * 32; u += 256) { int p = u >> 5, r = u & 31;
    ((float4*)f0s[p])[r] = ((const float4*)(feats0 + (size_t)(i0 + p) * kD0))[r]; }
  for (int u = t; u < kP * 48; u += 256) { int p = u / 48, r = u % 48;
    ((float4*)f1s[p])[r] = ((const float4*)(feats1 + (size_t)(i0 + p) * kD1 * 3))[r]; }
  for (int u = t; u < kP * 32; u += 256) { int p = u >> 5, r = u & 31;
    ((float4*)q0s[p])[r] = ((const float4*)(q0 + (size_t)(i0 + p) * kHD))[r]; }
  for (int u = t; u < kP * 96; u += 256) { int p = u / 96, r = u % 96;
    ((float4*)q1s[p])[r] = ((const float4*)(q1 + (size_t)(i0 + p) * kHD * 3))[r]; }
  if (t < kH) w1s[t] = log1pf(expf(hw1[t]));
  __syncthreads();

  float acc0[kP] = {};
  {
    const float4* wr = (const float4*)(Wskv0 + t * kD0);
    #pragma unroll
    for (int g = 0; g < 32; ++g) {
      float4 w = wr[g]; int c = g * 4;
      #pragma unroll
      for (int p = 0; p < kP; ++p)
        acc0[p] += w.x * f0s[p][c] + w.y * f0s[p][c + 1]
                 + w.z * f0s[p][c + 2] + w.w * f0s[p][c + 3];
    }
  }
  float acc1[kP][3] = {};
  {
    const float4* wr = (const float4*)(Wskv1 + t * kD1);
    #pragma unroll
    for (int g = 0; g < 16; ++g) {
      float4 w = wr[g]; int c = g * 4;
      float wv[4] = {w.x, w.y, w.z, w.w};
      #pragma unroll
      for (int q = 0; q < 4; ++q) {
        #pragma unroll
        for (int p = 0; p < kP; ++p) {
          const float* fp = &f1s[p][(c + q) * 3];
          acc1[p][0] += wv[q] * fp[0];
          acc1[p][1] += wv[q] * fp[1];
          acc1[p][2] += wv[q] * fp[2];
        }
      }
    }
  }
  if (t < kHD) {
    #pragma unroll
    for (int p = 0; p < kP; ++p) {
      sk0L[p][t] = acc0[p];
      sk1L[p][t * 3 + 0] = acc1[p][0];
      sk1L[p][t * 3 + 1] = acc1[p][1];
      sk1L[p][t * 3 + 2] = acc1[p][2];
    }
  } else {
    const int o = t - kHD;
    #pragma unroll
    for (int p = 0; p < kP; ++p) {
      ws_sv0[(size_t)(i0 + p) * kHD + o] = acc0[p];
      float* sp = ws_sv1 + (size_t)(i0 + p) * kHD * 3 + o * 3;
      sp[0] = acc1[p][0]; sp[1] = acc1[p][1]; sp[2] = acc1[p][2];
    }
  }
  __syncthreads();

  if (t < kP * 16) {
    const int p = t >> 4, idx = t & 15;
    const int h = idx & 7;
    const bool is_self = idx >= 8;
    float s0 = 0.f, s1 = 0.f, bias;
    if (is_self) {
      #pragma unroll
      for (int d = 0; d < kD; ++d) s0 += q0s[p][h * kD + d] * sk0L[p][h * kD + d];
      #pragma unroll
      for (int x = 0; x < 48; ++x) s1 += q1s[p][h * 48 + x] * sk1L[p][h * 48 + x];
      bias = self_bias[h];
    } else {
      #pragma unroll
      for (int d = 0; d < kD; ++d) s0 += q0s[p][h * kD + d] * nk0[h * kD + d];
      #pragma unroll
      for (int x = 0; x < 48; ++x) s1 += q1s[p][h * 48 + x] * nk1[h * 48 + x];
      bias = null_bias[h];
    }
    float total = (s0 * SCALE0 + bias + s1 * SCALE1 * w1s[h]) * SHARED_S;
    ws_sc[(size_t)(i0 + p) * 272 + h * 34 + (is_self ? 1 : 0)] = total;
  }
}

// ---------------------------------------------------------------------------
// K2: neighbor similarities + fused softmax. One position per block.
// QUAD-COALESCED k-loads: thread = (quad lane q, pair (j,h)). The quad's 4
// lanes load 4 consecutive float4s of the (j,h) key fragment, so every
// global_load_dwordx4 has lanes covering fully-consumed 64B lines (k0: the
// 64 lanes are 1KB CONTIGUOUS; k1: 16 fully-used 64B lines/instr). This
// removes the 64-lines-per-instruction TA divergence of the row-per-thread
// layout (the R1 bottleneck: 1.7 TB/s at 50% occupancy, VALU 5%).
// Dot partials reduced with 2x __shfl_xor within the quad; raw scores pass
// through an 8x33 LDS tile; 32-lane shuffle softmax unchanged.
// ---------------------------------------------------------------------------
__global__ __launch_bounds__(256, 4) void k2_sims(
    const float* __restrict__ q0, const float* __restrict__ q1,
    const float* __restrict__ k0, const float* __restrict__ k1,
    const float* __restrict__ edges, const float* __restrict__ Wbias,
    const float* __restrict__ hw1, const int* __restrict__ nmask,
    float* __restrict__ ws_sc)
{
  const int i = blockIdx.x;
  const int t = threadIdx.x;
  __shared__ __align__(16) float q0s[kHD];          // 128
  __shared__ __align__(16) float q1s[kHD * 3];      // 384
  __shared__ __align__(16) float edg[kN][kE + 1];   // 32 x 33 (pad)
  __shared__ float wbs[kH * kE];                    // [h][e]
  __shared__ float w1s[kH];
  __shared__ float scL[kH][kN + 1];                 // masked raw scores
  __shared__ int   nmL[kN];

  // stage q, edges, Wbias, mask
  if (t < 32) {
    ((float4*)q0s)[t] = ((const float4*)(q0 + (size_t)i * kHD))[t];
  } else if (t < 128) {
    int r = t - 32;
    ((float4*)q1s)[r] = ((const float4*)(q1 + (size_t)i * kHD * 3))[r];
  }
  {
    float4 v = ((const float4*)(edges + (size_t)i * kN * kE))[t];
    int j = t >> 3, e4 = (t & 7) * 4;
    float* dst = &edg[j][e4];
    dst[0] = v.x; dst[1] = v.y; dst[2] = v.z; dst[3] = v.w;
  }
  if (t < kH * kE) wbs[t] = Wbias[t];               // [h][e] row-major
  if (t < kH) w1s[t] = log1pf(expf(hw1[t]));
  if (t < kN) nmL[t] = nmask[(size_t)i * kN + t];
  __syncthreads();

  const int q  = t & 3;        // quad lane
  const int m  = t >> 2;       // pair index 0..63
  const int h  = m & 7;
  const int jl = m >> 3;       // 0..7
  const float w1h = w1s[h];

  // pass-invariant fragments -> registers (read LDS once)
  const float4 q0f = *((const float4*)(q0s + h * kD) + q);
  float4 q1f[3];
  #pragma unroll
  for (int pc = 0; pc < 3; ++pc)
    q1f[pc] = *((const float4*)(q1s + h * 48 + pc * 16) + q);
  float wbf[8];
  #pragma unroll
  for (int e = 0; e < 8; ++e) wbf[e] = wbs[h * kE + q * 8 + e];

  const float* k0base = k0 + (size_t)i * kN * kHD + h * kD + q * 4;
  const float* k1base = k1 + (size_t)i * kN * kHD * 3 + h * 48 + q * 4;

  // batch all 16 global loads (4 passes x (1 k0 + 3 k1)) before compute
  float4 kv0[4];
  float4 kv1[4][3];
  #pragma unroll
  for (int p = 0; p < 4; ++p) {
    const int j = p * 8 + jl;
    kv0[p] = *((const float4*)(k0base + (size_t)j * kHD));
    #pragma unroll
    for (int pc = 0; pc < 3; ++pc)
      kv1[p][pc] = *((const float4*)(k1base + (size_t)j * kHD * 3 + pc * 16));
  }

  #pragma unroll
  for (int p = 0; p < 4; ++p) {
    const int j = p * 8 + jl;
    float s0 = kv0[p].x * q0f.x + kv0[p].y * q0f.y
             + kv0[p].z * q0f.z + kv0[p].w * q0f.w;
    float s1 = 0.f;
    #pragma unroll
    for (int pc = 0; pc < 3; ++pc)
      s1 += kv1[p][pc].x * q1f[pc].x + kv1[p][pc].y * q1f[pc].y
          + kv1[p][pc].z * q1f[pc].z + kv1[p][pc].w * q1f[pc].w;
    float bias = 0.f;
    #pragma unroll
    for (int e = 0; e < 8; ++e) bias += edg[j][q * 8 + e] * wbf[e];

    float part = s0 * SCALE0 + bias + s1 * SCALE1 * w1h;
    part += __shfl_xor(part, 1);
    part += __shfl_xor(part, 2);
    float total = part * SHARED_S;
    if (q == 0) scL[h][j] = nmL[j] ? total : NEGV;
  }
  __syncthreads();

  // softmax over 34 = {null, self, 32 neighbors}; t = h*32 + j layout
  const int hh = t >> 5, jj = t & 31;
  float sc = scL[hh][jj];
  float* row = ws_sc + (size_t)i * 272 + hh * 34;
  float e0v = row[0], e1v = row[1];

  float mx = sc;
  #pragma unroll
  for (int off = 16; off > 0; off >>= 1) mx = fmaxf(mx, __shfl_xor(mx, off));
  mx = fmaxf(mx, fmaxf(e0v, e1v));
  float ex = __expf(sc - mx);
  float sum = ex;
  #pragma unroll
  for (int off = 16; off > 0; off >>= 1) sum += __shfl_xor(sum, off);
  float ee0 = __expf(e0v - mx), ee1 = __expf(e1v - mx);
  float inv = 1.f / (sum + ee0 + ee1);

  row[2 + jj] = ex * inv;
  if (jj == 0) row[0] = ee0 * inv;
  if (jj == 1) row[1] = ee1 * inv;
}

// ---------------------------------------------------------------------------
// K3: attn-weighted V accumulation ONLY (projection split into k4_proj).
// One (position, float4-chunk) per thread; batched loads (8 in flight).
// Writes o0/o1 IN PLACE over ws_sv0/ws_sv1: each thread reads its sv chunk
// before writing its o chunk at the same address (same thread, race-free).
// __launch_bounds__(256,4): cap VGPR<=128 -> 16 waves/CU.
// ---------------------------------------------------------------------------
__global__ __launch_bounds__(256, 4) void k3_accum(
    const float* __restrict__ v0, const float* __restrict__ v1,
    const float* __restrict__ nv0, const float* __restrict__ nv1,
    const float* __restrict__ ws_sc,
    float* __restrict__ ws_sv0, float* __restrict__ ws_sv1)
{
  const int i0 = blockIdx.x * kP3;
  const int t  = threadIdx.x;
  __shared__ __align__(16) float attnL[kP3][272];

  if (t < kP3 * 68) {
    int p = t / 68, r = t % 68;
    ((float4*)attnL[p])[r] = ((const float4*)(ws_sc + (size_t)(i0 + p) * 272))[r];
  }
  __syncthreads();

  // thread -> (p, s): p = t>>7, s = t&127. s<32: deg0 chunk s; else deg1 chunk s-32.
  const int p = t >> 7, i = i0 + p;
  const int s = t & 127;
  float4 acc;
  if (s < 32) {
    const int h = s >> 2;
    const float* at = attnL[p] + h * 34;
    float4 nv = ((const float4*)nv0)[s];
    float4 sv = ((const float4*)(ws_sv0 + (size_t)i * kHD))[s];
    acc.x = at[0] * nv.x + at[1] * sv.x;
    acc.y = at[0] * nv.y + at[1] * sv.y;
    acc.z = at[0] * nv.z + at[1] * sv.z;
    acc.w = at[0] * nv.w + at[1] * sv.w;
    const float4* vp = (const float4*)(v0 + (size_t)i * kN * kHD) + s;
    float4 vbuf[8];
    #pragma unroll
    for (int g = 0; g < 4; ++g) {
      #pragma unroll
      for (int r = 0; r < 8; ++r) vbuf[r] = vp[(g * 8 + r) * 32];
      #pragma unroll
      for (int r = 0; r < 8; ++r) {
        float a = at[2 + g * 8 + r];
        acc.x += a * vbuf[r].x; acc.y += a * vbuf[r].y;
        acc.z += a * vbuf[r].z; acc.w += a * vbuf[r].w;
      }
    }
    ((float4*)(ws_sv0 + (size_t)i * kHD))[s] = acc;   // o0 overlays sv0
  } else {
    const int s1 = s - 32;            // 0..95, never straddles a head (48%4==0)
    const int h = s1 / 12;
    const float* at = attnL[p] + h * 34;
    float4 nv = ((const float4*)nv1)[s1];
    float4 sv = ((const float4*)(ws_sv1 + (size_t)i * kHD * 3))[s1];
    acc.x = at[0] * nv.x + at[1] * sv.x;
    acc.y = at[0] * nv.y + at[1] * sv.y;
    acc.z = at[0] * nv.z + at[1] * sv.z;
    acc.w = at[0] * nv.w + at[1] * sv.w;
    const float4* vp = (const float4*)(v1 + (size_t)i * kN * kHD * 3) + s1;
    float4 vbuf[8];
    #pragma unroll
    for (int g = 0; g < 4; ++g) {
      #pragma unroll
      for (int r = 0; r < 8; ++r) vbuf[r] = vp[(g * 8 + r) * 96];
      #pragma unroll
      for (int r = 0; r < 8; ++r) {
        float a = at[2 + g * 8 + r];
        acc.x += a * vbuf[r].x; acc.y += a * vbuf[r].y;
        acc.z += a * vbuf[r].z; acc.w += a * vbuf[r].w;
      }
    }
    ((float4*)(ws_sv1 + (size_t)i * kHD * 3))[s1] = acc;  // o1 overlays sv1
  }
}

// ---------------------------------------------------------------------------
// K4: output projections. kPP=8 positions/block, 320 threads (one per output
// column: 128 deg0 + 192 deg1). W rows amortized over 8 positions. o0/o1
// staged in LDS (16.5 KB).
// ---------------------------------------------------------------------------
__global__ __launch_bounds__(320) void k4_proj(
    const float* __restrict__ ws_o0, const float* __restrict__ ws_o1,
    const float* __restrict__ Wout0, const float* __restrict__ Wout1,
    float* __restrict__ out, int n_total)
{
  const int i0 = blockIdx.x * kPP;
  const int t  = threadIdx.x;
  __shared__ __align__(16) float o0L[kPP][kHD];
  __shared__ __align__(16) float o1L[kPP][kHD * 3];

  for (int u = t; u < kPP * 32; u += 320) { int p = u >> 5, r = u & 31;
    ((float4*)o0L[p])[r] = ((const float4*)(ws_o0 + (size_t)(i0 + p) * kHD))[r]; }
  for (int u = t; u < kPP * 96; u += 320) { int p = u / 96, r = u % 96;
    ((float4*)o1L[p])[r] = ((const float4*)(ws_o1 + (size_t)(i0 + p) * kHD * 3))[r]; }
  __syncthreads();

  if (t < 128) {
    float acc[kPP] = {};
    const float4* wr = (const float4*)(Wout0 + t * kHD);
    #pragma unroll
    for (int g = 0; g < 32; ++g) {
      float4 w = wr[g]; int c = g * 4;
      #pragma unroll
      for (int p = 0; p < kPP; ++p)
        acc[p] += w.x * o0L[p][c] + w.y * o0L[p][c + 1]
                + w.z * o0L[p][c + 2] + w.w * o0L[p][c + 3];
    }
    #pragma unroll
    for (int p = 0; p < kPP; ++p) out[(size_t)(i0 + p) * kHD + t] = acc[p];
  } else {
    const int v2 = t - 128, o = v2 / 3, m = v2 - o * 3;
    float acc[kPP] = {};
    const float4* wr = (const float4*)(Wout1 + o * kHD);
    #pragma unroll
    for (int g = 0; g < 32; ++g) {
      float4 w = wr[g]; int c = g * 4;
      #pragma unroll
      for (int p = 0; p < kPP; ++p)
        acc[p] += w.x * o1L[p][(c + 0) * 3 + m] + w.y * o1L[p][(c + 1) * 3 + m]
                + w.z * o1L[p][(c + 2) * 3 + m] + w.w * o1L[p][(c + 3) * 3 + m];
    }
    #pragma unroll
    for (int p = 0; p < kPP; ++p)
      out[(size_t)n_total * kHD + (size_t)(i0 + p) * 192 + v2] = acc[p];
  }
}

extern "C" void kernel_launch(void* const* d_in, const int* in_sizes, int n_in,
                              void* d_out, int out_size, void* d_ws, size_t ws_size,
                              hipStream_t stream) {
  const int n = in_sizes[0] / kHD;  // 2048
  const float* q0     = (const float*)d_in[0];
  const float* k0     = (const float*)d_in[1];
  const float* v0     = (const float*)d_in[2];
  const float* q1     = (const float*)d_in[3];
  const float* k1     = (const float*)d_in[4];
  const float* v1     = (const float*)d_in[5];
  const float* feats0 = (const float*)d_in[6];
  const float* feats1 = (const float*)d_in[7];
  const float* edges  = (const float*)d_in[8];
  const float* Wskv0  = (const float*)d_in[9];
  const float* Wskv1  = (const float*)d_in[10];
  const float* Wbias  = (const float*)d_in[11];
  const float* sbias  = (const float*)d_in[12];
  const float* nbias  = (const float*)d_in[13];
  const float* nk0    = (const float*)d_in[14];
  const float* nv0    = (const float*)d_in[15];
  const float* nk1    = (const float*)d_in[16];
  const float* nv1    = (const float*)d_in[17];
  const float* hw1    = (const float*)d_in[18];
  const float* Wout0  = (const float*)d_in[19];
  const float* Wout1  = (const float*)d_in[20];
  const int*   nmask  = (const int*)d_in[21];

  float* ws     = (float*)d_ws;
  float* ws_sc  = ws;                                      // n*272
  float* ws_sv0 = ws + (size_t)n * 272;                    // n*128 (then o0)
  float* ws_sv1 = ws + (size_t)n * 272 + (size_t)n * 128;  // n*384 (then o1)

  k1_selfkv<<<n / kP, 256, 0, stream>>>(q0, q1, feats0, feats1, Wskv0, Wskv1,
                                        sbias, nbias, nk0, nk1, hw1,
                                        ws_sc, ws_sv0, ws_sv1);
  k2_sims<<<n, 256, 0, stream>>>(q0, q1, k0, k1, edges, Wbias, hw1, nmask, ws_sc);
  k3_accum<<<n / kP3, 256, 0, stream>>>(v0, v1, nv0, nv1, ws_sc, ws_sv0, ws_sv1);
  k4_proj<<<n / kPP, 320, 0, stream>>>(ws_sv0, ws_sv1, Wout0, Wout1, (float*)d_out, n);
}

// Round 5
// 324.613 us; speedup vs baseline: 1.1214x; 1.0778x over previous
//
#include <hip/hip_runtime.h>

// Problem constants
constexpr int kH  = 8;     // heads
constexpr int kD  = 16;    // dim per head
constexpr int kHD = 128;   // H*D
constexpr int kN  = 32;    // neighbors
constexpr int kE  = 32;    // edge feature dim
constexpr int kD0 = 128;   // feats0 channels
constexpr int kD1 = 64;    // feats1 channels
constexpr int kPos = 2;    // positions per block

constexpr float SCALE0   = 0.25f;                 // 1/sqrt(16)
constexpr float SCALE1   = 0.14433756729740643f;  // 1/sqrt(48)
constexpr float SHARED_S = 0.70710678118654752f;  // sqrt(0.5)
constexpr float NEGV     = -1e9f;

// ---------------------------------------------------------------------------
// Fully fused SE3 attention: all 4 phases (selfKV, scores+softmax, attn*V,
// output proj) for 2 positions per block. Phases are per-position independent,
// so different blocks on a CU occupy different phases simultaneously -> the
// memory phase of one block overlaps the compute phase of another (the
// 4-kernel structure globally serialized phases). No workspace traffic at all:
// sk/sv/attn/o live in LDS (~30 KB/block -> 4 blocks/CU at 16 waves).
// W phases use quad-cooperative rows: a quad covers one W row with 4
// contiguous 16B chunks -> every W load instruction touches 16 fully-consumed
// 64B lines (row-per-thread touched 64 lines/instr at 1/4 use).
// ---------------------------------------------------------------------------
__global__ __launch_bounds__(256, 4) void se3_fused(
    const float* __restrict__ q0, const float* __restrict__ q1,
    const float* __restrict__ k0, const float* __restrict__ k1,
    const float* __restrict__ v0, const float* __restrict__ v1,
    const float* __restrict__ feats0, const float* __restrict__ feats1,
    const float* __restrict__ edges,
    const float* __restrict__ Wskv0, const float* __restrict__ Wskv1,
    const float* __restrict__ Wbias,
    const float* __restrict__ sbias, const float* __restrict__ nbias,
    const float* __restrict__ nk0, const float* __restrict__ nk1,
    const float* __restrict__ nv0, const float* __restrict__ nv1,
    const float* __restrict__ hw1,
    const float* __restrict__ Wout0, const float* __restrict__ Wout1,
    const int* __restrict__ nmask,
    float* __restrict__ out, int n_total)
{
  const int i0 = blockIdx.x * kPos;
  const int t  = threadIdx.x;

  __shared__ __align__(16) float f0s[kPos][kD0];        // 256
  __shared__ __align__(16) float f1s[kPos][kD1 * 3];    // 384
  __shared__ __align__(16) float q0s[kPos][kHD];        // 256
  __shared__ __align__(16) float q1s[kPos][kHD * 3];    // 768
  __shared__ float edg[kPos][kN * (kE + 1)];            // 2112 (pad 33)
  __shared__ float wbs[kH * kE];                        // 256  [h][e]
  __shared__ float w1s[kH];
  __shared__ int   nmL[kPos][kN];
  __shared__ float sk0[kPos][kHD];                      // 256
  __shared__ __align__(16) float sk1[kPos][kHD * 3];    // 768
  __shared__ __align__(16) float sv0[kPos][kHD];        // 256
  __shared__ __align__(16) float sv1[kPos][kHD * 3];    // 768
  __shared__ float sc[kPos][kH][36];                    // 576 (34 used, pad)
  __shared__ __align__(16) float o0[kPos][kHD];         // 256
  __shared__ __align__(16) float o1[kPos][kHD * 3];     // 768

  // ---------------- Phase 0: stage ----------------
  if (t < kPos * 32) { int p = t >> 5, r = t & 31;
    ((float4*)f0s[p])[r] = ((const float4*)(feats0 + (size_t)(i0 + p) * kD0))[r]; }
  else if (t < kPos * 32 + kPos * 48) { int u = t - kPos * 32, p = u / 48, r = u % 48;
    ((float4*)f1s[p])[r] = ((const float4*)(feats1 + (size_t)(i0 + p) * kD1 * 3))[r]; }
  if (t >= 160 && t < 160 + kPos * 32) { int u = t - 160, p = u >> 5, r = u & 31;
    ((float4*)q0s[p])[r] = ((const float4*)(q0 + (size_t)(i0 + p) * kHD))[r]; }
  {  // q1: 192 float4
    int u = t; if (u < kPos * 96) { int p = u / 96, r = u % 96;
      ((float4*)q1s[p])[r] = ((const float4*)(q1 + (size_t)(i0 + p) * kHD * 3))[r]; }
  }
  for (int u = t; u < kPos * 256; u += 256) { int p = u >> 8, r = u & 255;
    float4 v = ((const float4*)(edges + (size_t)(i0 + p) * kN * kE))[r];
    int j = r >> 3, e4 = (r & 7) * 4;
    float* dst = &edg[p][j * 33 + e4];
    dst[0] = v.x; dst[1] = v.y; dst[2] = v.z; dst[3] = v.w; }
  if (t < kH * kE) wbs[t] = Wbias[t];
  if (t < kH) w1s[t] = log1pf(expf(hw1[t]));
  if (t < kPos * kN) { int p = t >> 5, j = t & 31;
    nmL[p][j] = nmask[(size_t)(i0 + p) * kN + j]; }
  __syncthreads();

  const int q4 = t & 3;        // quad lane
  const int qg = t >> 2;       // quad group 0..63

  // ---------------- Phase A: selfKV (quad-cooperative W rows) ----------------
  #pragma unroll
  for (int pass = 0; pass < 4; ++pass) {
    const int r = qg + 64 * pass;          // W row 0..255
    const float4* w0r = (const float4*)(Wskv0 + (size_t)r * kD0);
    float a0[kPos] = {};
    #pragma unroll
    for (int g = 0; g < 8; ++g) {
      float4 w = w0r[q4 + 4 * g]; int c = (q4 + 4 * g) * 4;
      #pragma unroll
      for (int p = 0; p < kPos; ++p)
        a0[p] += w.x * f0s[p][c] + w.y * f0s[p][c + 1]
               + w.z * f0s[p][c + 2] + w.w * f0s[p][c + 3];
    }
    const float4* w1r = (const float4*)(Wskv1 + (size_t)r * kD1);
    float a1[kPos][3] = {};
    #pragma unroll
    for (int g = 0; g < 4; ++g) {
      float4 w = w1r[q4 + 4 * g]; int c = (q4 + 4 * g) * 4;
      float wv[4] = {w.x, w.y, w.z, w.w};
      #pragma unroll
      for (int k = 0; k < 4; ++k) {
        #pragma unroll
        for (int p = 0; p < kPos; ++p) {
          const float* fp = &f1s[p][(c + k) * 3];
          a1[p][0] += wv[k] * fp[0];
          a1[p][1] += wv[k] * fp[1];
          a1[p][2] += wv[k] * fp[2];
        }
      }
    }
    #pragma unroll
    for (int p = 0; p < kPos; ++p) {
      a0[p] += __shfl_xor(a0[p], 1); a0[p] += __shfl_xor(a0[p], 2);
      #pragma unroll
      for (int c = 0; c < 3; ++c) {
        a1[p][c] += __shfl_xor(a1[p][c], 1);
        a1[p][c] += __shfl_xor(a1[p][c], 2);
      }
    }
    if (q4 == 0) {
      if (r < kHD) {
        #pragma unroll
        for (int p = 0; p < kPos; ++p) {
          sk0[p][r] = a0[p];
          sk1[p][r * 3 + 0] = a1[p][0];
          sk1[p][r * 3 + 1] = a1[p][1];
          sk1[p][r * 3 + 2] = a1[p][2];
        }
      } else {
        const int o = r - kHD;
        #pragma unroll
        for (int p = 0; p < kPos; ++p) {
          sv0[p][o] = a0[p];
          sv1[p][o * 3 + 0] = a1[p][0];
          sv1[p][o * 3 + 1] = a1[p][1];
          sv1[p][o * 3 + 2] = a1[p][2];
        }
      }
    }
  }
  __syncthreads();

  // ---------------- Phase B0: null/self scores (t<32) ----------------
  if (t < kPos * 16) {
    const int p = t >> 4, idx = t & 15;
    const int h = idx & 7;
    const bool is_self = idx >= 8;
    float s0 = 0.f, s1 = 0.f, bias;
    if (is_self) {
      #pragma unroll
      for (int d = 0; d < kD; ++d) s0 += q0s[p][h * kD + d] * sk0[p][h * kD + d];
      #pragma unroll
      for (int x = 0; x < 48; ++x) s1 += q1s[p][h * 48 + x] * sk1[p][h * 48 + x];
      bias = sbias[h];
    } else {
      #pragma unroll
      for (int d = 0; d < kD; ++d) s0 += q0s[p][h * kD + d] * nk0[h * kD + d];
      #pragma unroll
      for (int x = 0; x < 48; ++x) s1 += q1s[p][h * 48 + x] * nk1[h * 48 + x];
      bias = nbias[h];
    }
    sc[p][h][is_self ? 1 : 0] =
        (s0 * SCALE0 + bias + s1 * SCALE1 * w1s[h]) * SHARED_S;
  }

  // ---------------- Phase B1: neighbor scores (quad-coalesced k loads) -------
  {
    const int h  = qg & 7;
    const int jl = qg >> 3;     // 0..7
    const float w1h = w1s[h];
    float wbf[8];
    #pragma unroll
    for (int e = 0; e < 8; ++e) wbf[e] = wbs[h * kE + q4 * 8 + e];

    #pragma unroll
    for (int p = 0; p < kPos; ++p) {
      const int i = i0 + p;
      const float4 q0f = *((const float4*)(q0s[p] + h * kD) + q4);
      float4 q1f[3];
      #pragma unroll
      for (int pc = 0; pc < 3; ++pc)
        q1f[pc] = *((const float4*)(q1s[p] + h * 48 + pc * 16) + q4);

      const float* k0base = k0 + (size_t)i * kN * kHD + h * kD + q4 * 4;
      const float* k1base = k1 + (size_t)i * kN * kHD * 3 + h * 48 + q4 * 4;

      float4 kv0[4];
      float4 kv1[4][3];
      #pragma unroll
      for (int pp = 0; pp < 4; ++pp) {
        const int j = pp * 8 + jl;
        kv0[pp] = *((const float4*)(k0base + (size_t)j * kHD));
        #pragma unroll
        for (int pc = 0; pc < 3; ++pc)
          kv1[pp][pc] = *((const float4*)(k1base + (size_t)j * kHD * 3 + pc * 16));
      }

      #pragma unroll
      for (int pp = 0; pp < 4; ++pp) {
        const int j = pp * 8 + jl;
        float s0 = kv0[pp].x * q0f.x + kv0[pp].y * q0f.y
                 + kv0[pp].z * q0f.z + kv0[pp].w * q0f.w;
        float s1 = 0.f;
        #pragma unroll
        for (int pc = 0; pc < 3; ++pc)
          s1 += kv1[pp][pc].x * q1f[pc].x + kv1[pp][pc].y * q1f[pc].y
              + kv1[pp][pc].z * q1f[pc].z + kv1[pp][pc].w * q1f[pc].w;
        float bias = 0.f;
        #pragma unroll
        for (int e = 0; e < 8; ++e) bias += edg[p][j * 33 + q4 * 8 + e] * wbf[e];

        float part = s0 * SCALE0 + bias + s1 * SCALE1 * w1h;
        part += __shfl_xor(part, 1);
        part += __shfl_xor(part, 2);
        if (q4 == 0) sc[p][h][2 + j] = nmL[p][j] ? part * SHARED_S : NEGV;
      }
    }
  }
  __syncthreads();

  // ---------------- Phase C: softmax (16 rows x 16 lanes) ----------------
  {
    const int row = t >> 4;          // 0..15
    const int p = row >> 3, h = row & 7, l = t & 15;
    float* rp = sc[p][h];
    float va = rp[2 + l], vb = rp[2 + l + 16];
    float mx = fmaxf(va, vb);
    #pragma unroll
    for (int off = 8; off > 0; off >>= 1) mx = fmaxf(mx, __shfl_xor(mx, off));
    float e0v = rp[0], e1v = rp[1];
    mx = fmaxf(mx, fmaxf(e0v, e1v));
    float ea = __expf(va - mx), eb = __expf(vb - mx);
    float sum = ea + eb;
    #pragma unroll
    for (int off = 8; off > 0; off >>= 1) sum += __shfl_xor(sum, off);
    float ee0 = __expf(e0v - mx), ee1 = __expf(e1v - mx);
    float inv = 1.f / (sum + ee0 + ee1);
    rp[2 + l] = ea * inv;
    rp[2 + l + 16] = eb * inv;
    if (l == 0) rp[0] = ee0 * inv;
    if (l == 1) rp[1] = ee1 * inv;
  }
  __syncthreads();

  // ---------------- Phase D: attn-weighted V accumulate ----------------
  {
    const int p = t >> 7, i = i0 + p;
    const int s = t & 127;
    float4 acc;
    if (s < 32) {
      const int h = s >> 2;
      const float* at = sc[p][h];
      float4 nv = ((const float4*)nv0)[s];
      float4 sv = ((const float4*)sv0[p])[s];
      acc.x = at[0] * nv.x + at[1] * sv.x;
      acc.y = at[0] * nv.y + at[1] * sv.y;
      acc.z = at[0] * nv.z + at[1] * sv.z;
      acc.w = at[0] * nv.w + at[1] * sv.w;
      const float4* vp = (const float4*)(v0 + (size_t)i * kN * kHD) + s;
      float4 vbuf[8];
      #pragma unroll
      for (int g = 0; g < 4; ++g) {
        #pragma unroll
        for (int r = 0; r < 8; ++r) vbuf[r] = vp[(g * 8 + r) * 32];
        #pragma unroll
        for (int r = 0; r < 8; ++r) {
          float a = at[2 + g * 8 + r];
          acc.x += a * vbuf[r].x; acc.y += a * vbuf[r].y;
          acc.z += a * vbuf[r].z; acc.w += a * vbuf[r].w;
        }
      }
      ((float4*)o0[p])[s] = acc;
    } else {
      const int s1 = s - 32;           // 0..95 (head-aligned: 48%4==0)
      const int h = s1 / 12;
      const float* at = sc[p][h];
      float4 nv = ((const float4*)nv1)[s1];
      float4 sv = ((const float4*)sv1[p])[s1];
      acc.x = at[0] * nv.x + at[1] * sv.x;
      acc.y = at[0] * nv.y + at[1] * sv.y;
      acc.z = at[0] * nv.z + at[1] * sv.z;
      acc.w = at[0] * nv.w + at[1] * sv.w;
      const float4* vp = (const float4*)(v1 + (size_t)i * kN * kHD * 3) + s1;
      float4 vbuf[8];
      #pragma unroll
      for (int g = 0; g < 4; ++g) {
        #pragma unroll
        for (int r = 0; r < 8; ++r) vbuf[r] = vp[(g * 8 + r) * 96];
        #pragma unroll
        for (int r = 0; r < 8; ++r) {
          float a = at[2 + g * 8 + r];
          acc.x += a * vbuf[r].x; acc.y += a * vbuf[r].y;
          acc.z += a * vbuf[r].z; acc.w += a * vbuf[r].w;
        }
      }
      ((float4*)o1[p])[s1] = acc;
    }
  }
  __syncthreads();

  // ---------------- Phase E: output projections (quad-cooperative) ----------
  #pragma unroll
  for (int pass = 0; pass < 5; ++pass) {
    const int u = qg + 64 * pass;          // 0..319 (wave-uniform branch)
    if (u < 128) {
      const float4* wr = (const float4*)(Wout0 + (size_t)u * kHD);
      float a[kPos] = {};
      #pragma unroll
      for (int g = 0; g < 8; ++g) {
        float4 w = wr[q4 + 4 * g]; int c = (q4 + 4 * g) * 4;
        #pragma unroll
        for (int p = 0; p < kPos; ++p)
          a[p] += w.x * o0[p][c] + w.y * o0[p][c + 1]
                + w.z * o0[p][c + 2] + w.w * o0[p][c + 3];
      }
      #pragma unroll
      for (int p = 0; p < kPos; ++p) {
        a[p] += __shfl_xor(a[p], 1); a[p] += __shfl_xor(a[p], 2);
      }
      if (q4 == 0) {
        #pragma unroll
        for (int p = 0; p < kPos; ++p)
          out[(size_t)(i0 + p) * kHD + u] = a[p];
      }
    } else {
      const int v2 = u - 128, o = v2 / 3, m = v2 - o * 3;
      const float4* wr = (const float4*)(Wout1 + (size_t)o * kHD);
      float a[kPos] = {};
      #pragma unroll
      for (int g = 0; g < 8; ++g) {
        float4 w = wr[q4 + 4 * g]; int c = (q4 + 4 * g) * 4;
        #pragma unroll
        for (int p = 0; p < kPos; ++p)
          a[p] += w.x * o1[p][(c + 0) * 3 + m] + w.y * o1[p][(c + 1) * 3 + m]
                + w.z * o1[p][(c + 2) * 3 + m] + w.w * o1[p][(c + 3) * 3 + m];
      }
      #pragma unroll
      for (int p = 0; p < kPos; ++p) {
        a[p] += __shfl_xor(a[p], 1); a[p] += __shfl_xor(a[p], 2);
      }
      if (q4 == 0) {
        #pragma unroll
        for (int p = 0; p < kPos; ++p)
          out[(size_t)n_total * kHD + (size_t)(i0 + p) * 192 + v2] = a[p];
      }
    }
  }
}

extern "C" void kernel_launch(void* const* d_in, const int* in_sizes, int n_in,
                              void* d_out, int out_size, void* d_ws, size_t ws_size,
                              hipStream_t stream) {
  const int n = in_sizes[0] / kHD;  // 2048
  const float* q0     = (const float*)d_in[0];
  const float* k0     = (const float*)d_in[1];
  const float* v0     = (const float*)d_in[2];
  const float* q1     = (const float*)d_in[3];
  const float* k1     = (const float*)d_in[4];
  const float* v1     = (const float*)d_in[5];
  const float* feats0 = (const float*)d_in[6];
  const float* feats1 = (const float*)d_in[7];
  const float* edges  = (const float*)d_in[8];
  const float* Wskv0  = (const float*)d_in[9];
  const float* Wskv1  = (const float*)d_in[10];
  const float* Wbias  = (const float*)d_in[11];
  const float* sbias  = (const float*)d_in[12];
  const float* nbias  = (const float*)d_in[13];
  const float* nk0    = (const float*)d_in[14];
  const float* nv0    = (const float*)d_in[15];
  const float* nk1    = (const float*)d_in[16];
  const float* nv1    = (const float*)d_in[17];
  const float* hw1    = (const float*)d_in[18];
  const float* Wout0  = (const float*)d_in[19];
  const float* Wout1  = (const float*)d_in[20];
  const int*   nmask  = (const int*)d_in[21];

  se3_fused<<<n / kPos, 256, 0, stream>>>(
      q0, q1, k0, k1, v0, v1, feats0, feats1, edges,
      Wskv0, Wskv1, Wbias, sbias, nbias, nk0, nk1, nv0, nv1, hw1,
      Wout0, Wout1, nmask, (float*)d_out, n);
}